// Round 1
// 1382.758 us; speedup vs baseline: 1.2597x; 1.2597x over previous
//
#include <hip/hip_runtime.h>
#include <hip/hip_bf16.h>
#include <math.h>
#include <stdint.h>

#define PI_F 3.14159265358979323846f

typedef __hip_bfloat16 bf16;
typedef __attribute__((ext_vector_type(8))) short short8;   // 8 x bf16 (4 VGPRs)
typedef __attribute__((ext_vector_type(4))) float floatx4;

static constexpr int DIM = 4096;

// ---------- helpers ----------
__device__ __forceinline__ unsigned short f2bf_bits(float f) {
    __hip_bfloat16 h = __float2bfloat16(f);
    return __builtin_bit_cast(unsigned short, h);
}
__device__ __forceinline__ float bf2f_bits(unsigned short u) {
    return __builtin_bit_cast(float, ((unsigned int)u) << 16);
}
// async global->LDS, 16B per lane; LDS dest is wave-uniform base (+lane*16 implicit)
__device__ __forceinline__ void load_lds16(const void* gsrc, void* lds) {
    __builtin_amdgcn_global_load_lds(
        (__attribute__((address_space(1))) void*)gsrc,
        (__attribute__((address_space(3))) void*)lds,
        16, 0, 0);
}

// ---------- cast fp32 -> bf16, 4 elems/thread ----------
__global__ __launch_bounds__(256)
void cast_f32_bf16(const float* __restrict__ src, unsigned short* __restrict__ dst, int n4) {
    int i = blockIdx.x * 256 + threadIdx.x;
    if (i < n4) {
        float4 v = ((const float4*)src)[i];
        ushort4 o;
        o.x = f2bf_bits(v.x); o.y = f2bf_bits(v.y);
        o.z = f2bf_bits(v.z); o.w = f2bf_bits(v.w);
        ((ushort4*)dst)[i] = o;
    }
}

// ---------- pack Wk,Wq into Wt[k][p] fp32 (p<64: Wk, p>=64: Wq) ----------
__global__ __launch_bounds__(256)
void transpose_wkq(const float* __restrict__ Wk, const float* __restrict__ Wq,
                   float* __restrict__ Wt) {
    int idx = blockIdx.x * 256 + threadIdx.x;   // over 4096*128
    int k = idx >> 7, p = idx & 127;
    float v = (p < 64) ? Wk[(size_t)p * DIM + k] : Wq[(size_t)(p - 64) * DIM + k];
    Wt[idx] = v;
}

// ---------- phase GEMM, K-split partials (fp32, exact) ----------
// Grid: (256, 8).  blockIdx.x -> 32-row tile, blockIdx.y -> 512-wide K slice.
// 256 thr = 8 row-groups x 32 col-groups; each thread: 4 rows x 4 cols.
// Writes part[s][row][col] fp32.  Occupancy fix vs fused version: 2048 blocks
// (was 256 -> 1 wave/SIMD, VALUBusy 14%); no LDS, low VGPR -> up to 32 waves/CU.
__global__ __launch_bounds__(256)
void phase_partial(const float* __restrict__ x, const float* __restrict__ Wt,
                   float* __restrict__ part)
{
    const int tid = threadIdx.x;
    const int rg  = tid >> 5;          // 0..7 -> rows rg*4..+4
    const int cg  = tid & 31;          // 0..31 -> cols cg*4..+4
    const size_t row0 = (size_t)blockIdx.x * 32;
    const int s   = blockIdx.y;        // K slice 0..7
    const int kbeg = s * 512, kend = kbeg + 512;

    float acc[4][4] = {};
    const float* xp = x + (row0 + (size_t)rg * 4) * DIM;

    for (int k = kbeg; k < kend; k += 4) {
        const float4 w0 = *(const float4*)(Wt + (size_t)(k + 0) * 128 + cg * 4);
        const float4 w1 = *(const float4*)(Wt + (size_t)(k + 1) * 128 + cg * 4);
        const float4 w2 = *(const float4*)(Wt + (size_t)(k + 2) * 128 + cg * 4);
        const float4 w3 = *(const float4*)(Wt + (size_t)(k + 3) * 128 + cg * 4);
        #pragma unroll
        for (int r = 0; r < 4; ++r) {
            const float4 xv = *(const float4*)(xp + (size_t)r * DIM + k);
            acc[r][0] += xv.x * w0.x + xv.y * w1.x + xv.z * w2.x + xv.w * w3.x;
            acc[r][1] += xv.x * w0.y + xv.y * w1.y + xv.z * w2.y + xv.w * w3.y;
            acc[r][2] += xv.x * w0.z + xv.y * w1.z + xv.z * w2.z + xv.w * w3.z;
            acc[r][3] += xv.x * w0.w + xv.y * w1.w + xv.z * w2.w + xv.w * w3.w;
        }
    }

    #pragma unroll
    for (int r = 0; r < 4; ++r) {
        float4 st;
        st.x = acc[r][0]; st.y = acc[r][1]; st.z = acc[r][2]; st.w = acc[r][3];
        *(float4*)(part + ((size_t)s * 8192 + row0 + rg * 4 + r) * 128 + cg * 4) = st;
    }
}

// ---------- finalize: sum K slices, tanh/cos/softplus -> scale[row] ----------
// One wave per row (lane p handles phase p and phase 64+p); 4 rows per block.
__global__ __launch_bounds__(256)
void phase_finalize(const float* __restrict__ part, const float* __restrict__ bk,
                    const float* __restrict__ bq, float* __restrict__ scale)
{
    const int tid  = threadIdx.x;
    const int lane = tid & 63;
    const size_t row = (size_t)blockIdx.x * 4 + (tid >> 6);
    float sk = 0.f, sq = 0.f;
    #pragma unroll
    for (int s = 0; s < 8; ++s) {
        const float* pr = part + ((size_t)s * 8192 + row) * 128;
        sk += pr[lane];
        sq += pr[64 + lane];
    }
    const float kp = PI_F * tanhf(sk + bk[lane]);
    const float qp = PI_F * tanhf(sq + bq[lane]);
    float c = cosf(kp - qp);
    #pragma unroll
    for (int off = 32; off; off >>= 1) c += __shfl_down(c, off, 64);
    if (lane == 0) {
        const float a = c;
        const float gsp = log1pf(expf(a * (1.f / 64.f) + 0.5f));   // softplus
        scale[row] = a * gsp * (1.f / 64.f);
    }
}

// ---------- m97-style bf16 MFMA GEMM: C[m][n] = sum_k A[m][k]*Bm[n][k] (+epilogue) ----------
// MODE 1: nbuf = bf16( (dot + bias[n]) * scale[m] )            (V path, bf16 out)
// MODE 2: out  = fp32( dot + bias[n] + xres[m][n] )            (output path, fp32 out)
template <int MODE>
__global__ __launch_bounds__(256)
void gemm_bt(const bf16* __restrict__ A, const bf16* __restrict__ Bm,
             const float* __restrict__ bias, const float* __restrict__ scale,
             const float* __restrict__ xres, bf16* __restrict__ outBf,
             float* __restrict__ outF, int N)
{
    constexpr int K = 4096;
    __shared__ __align__(16) bf16 As[128 * 32];
    __shared__ __align__(16) bf16 Bs[128 * 32];
    const int tid  = threadIdx.x;
    const int lane = tid & 63;
    const int wave = tid >> 6;
    const size_t bm = (size_t)blockIdx.x * 128;
    const size_t bn = (size_t)blockIdx.y * 128;
    const int wr  = (wave >> 1) * 64;
    const int wc  = (wave & 1) * 64;
    const int q   = lane >> 4;
    const int m16 = lane & 15;

    floatx4 acc[4][4] = {};

    // staging: chunk c (16B = 8 bf16) -> tile row c>>2, k-col (c&3)*8; thread does chunks tid, tid+256
    const int r0 = tid >> 2,         col0 = (tid & 3) << 3;
    const int r1 = (tid + 256) >> 2, col1 = (tid & 3) << 3;
    bf16* lA0 = As + (size_t)(wave * 64) * 8;          // wave-uniform LDS bases
    bf16* lA1 = As + (size_t)(256 + wave * 64) * 8;
    bf16* lB0 = Bs + (size_t)(wave * 64) * 8;
    bf16* lB1 = Bs + (size_t)(256 + wave * 64) * 8;
    const bf16* gA0 = A  + (bm + r0) * K + col0;
    const bf16* gA1 = A  + (bm + r1) * K + col1;
    const bf16* gB0 = Bm + (bn + r0) * K + col0;
    const bf16* gB1 = Bm + (bn + r1) * K + col1;

    for (int k0 = 0; k0 < K; k0 += 32) {
        load_lds16(gA0 + k0, lA0);
        load_lds16(gA1 + k0, lA1);
        load_lds16(gB0 + k0, lB0);
        load_lds16(gB1 + k0, lB1);
        __syncthreads();
        short8 af[4], bfv[4];
        #pragma unroll
        for (int i = 0; i < 4; ++i)
            af[i] = *(const short8*)(As + (size_t)(wr + i * 16 + m16) * 32 + q * 8);
        #pragma unroll
        for (int j = 0; j < 4; ++j)
            bfv[j] = *(const short8*)(Bs + (size_t)(wc + j * 16 + m16) * 32 + q * 8);
        #pragma unroll
        for (int i = 0; i < 4; ++i) {
            #pragma unroll
            for (int j = 0; j < 4; ++j)
                acc[i][j] = __builtin_amdgcn_mfma_f32_16x16x32_bf16(af[i], bfv[j], acc[i][j], 0, 0, 0);
        }
        __syncthreads();
    }

    // epilogue: C/D layout col=lane&15, row=(lane>>4)*4+reg
    #pragma unroll
    for (int i = 0; i < 4; ++i) {
        #pragma unroll
        for (int j = 0; j < 4; ++j) {
            const size_t col = bn + wc + j * 16 + m16;
            const float bv = bias[col];
            #pragma unroll
            for (int r = 0; r < 4; ++r) {
                const size_t row = bm + wr + i * 16 + q * 4 + r;
                float v = acc[i][j][r] + bv;
                if (MODE == 1) {
                    v *= scale[row];
                    outBf[row * (size_t)N + col] = __float2bfloat16(v);
                } else {
                    v += xres[row * (size_t)DIM + col];
                    outF[row * (size_t)N + col] = v;    // fp32 output
                }
            }
        }
    }
}

// ---------- in-place LayerNorm over each row of bf16 buffer ----------
__global__ __launch_bounds__(256)
void ln_kernel(bf16* __restrict__ o, const float* __restrict__ g, const float* __restrict__ b)
{
    const size_t row = blockIdx.x;
    unsigned short* p = (unsigned short*)(o + row * DIM);
    const int tid = threadIdx.x;
    float s = 0.f, s2 = 0.f;
    float vals[16];
    #pragma unroll
    for (int c = 0; c < 4; ++c) {
        ushort4 u = ((const ushort4*)p)[tid + c * 256];
        float v0 = bf2f_bits(u.x), v1 = bf2f_bits(u.y);
        float v2 = bf2f_bits(u.z), v3 = bf2f_bits(u.w);
        vals[c * 4 + 0] = v0; vals[c * 4 + 1] = v1;
        vals[c * 4 + 2] = v2; vals[c * 4 + 3] = v3;
        s  += v0 + v1 + v2 + v3;
        s2 += v0 * v0 + v1 * v1 + v2 * v2 + v3 * v3;
    }
    #pragma unroll
    for (int off = 32; off; off >>= 1) {
        s  += __shfl_down(s, off, 64);
        s2 += __shfl_down(s2, off, 64);
    }
    __shared__ float red[2][4];
    const int wv = tid >> 6, ln = tid & 63;
    if (ln == 0) { red[0][wv] = s; red[1][wv] = s2; }
    __syncthreads();
    const float ts  = red[0][0] + red[0][1] + red[0][2] + red[0][3];
    const float ts2 = red[1][0] + red[1][1] + red[1][2] + red[1][3];
    const float mean = ts * (1.f / 4096.f);
    const float var  = ts2 * (1.f / 4096.f) - mean * mean;
    const float rstd = rsqrtf(var + 1e-5f);
    #pragma unroll
    for (int c = 0; c < 4; ++c) {
        const int idx = (tid + c * 256) * 4;
        ushort4 u;
        u.x = f2bf_bits((vals[c * 4 + 0] - mean) * rstd * g[idx + 0] + b[idx + 0]);
        u.y = f2bf_bits((vals[c * 4 + 1] - mean) * rstd * g[idx + 1] + b[idx + 1]);
        u.z = f2bf_bits((vals[c * 4 + 2] - mean) * rstd * g[idx + 2] + b[idx + 2]);
        u.w = f2bf_bits((vals[c * 4 + 3] - mean) * rstd * g[idx + 3] + b[idx + 3]);
        ((ushort4*)p)[tid + c * 256] = u;
    }
}

extern "C" void kernel_launch(void* const* d_in, const int* in_sizes, int n_in,
                              void* d_out, int out_size, void* d_ws, size_t ws_size,
                              hipStream_t stream)
{
    // Inputs are fp32 per the reference contract (round-2 NaN proved they are
    // not bf16). Output is fp32 (round-1's 10.7 absmax matched the
    // bf16-written/fp32-read + half-unwritten-buffer signature).
    const float* x   = (const float*)d_in[0];
    const float* Wk  = (const float*)d_in[1];
    const float* bk  = (const float*)d_in[2];
    const float* Wq  = (const float*)d_in[3];
    const float* bq  = (const float*)d_in[4];
    const float* Wv  = (const float*)d_in[5];
    const float* bv  = (const float*)d_in[6];
    const float* lng = (const float*)d_in[7];
    const float* lnb = (const float*)d_in[8];
    const float* Wo  = (const float*)d_in[9];
    const float* bo  = (const float*)d_in[10];

    char* ws = (char*)d_ws;
    bf16*  x_bf  = (bf16*)(ws);                       //  64 MiB  [8192][4096]
    bf16*  Wv_bf = (bf16*)(ws + 67108864);            //  32 MiB  [4096][4096]
    bf16*  Wo_bf = (bf16*)(ws + 100663296);           //  32 MiB  [4096][4096]
    float* Wt    = (float*)(ws + 134217728);          //   2 MiB  [4096][128]
    float* scl   = (float*)(ws + 136314880);          //  32 KiB  [8192]
    bf16*  nbuf  = (bf16*)(ws + 136347648);           //  64 MiB  [8192][4096]
    // phase partials alias the nbuf region (33.5 MiB < 64 MiB): they are fully
    // consumed by phase_finalize before gemm_bt<1> writes nbuf.
    float* part  = (float*)nbuf;                      //  [8][8192][128] fp32
    // total ws use: ~194 MiB

    cast_f32_bf16<<<8388608 / 256, 256, 0, stream>>>(x,  (unsigned short*)x_bf,  8388608);
    cast_f32_bf16<<<4194304 / 256, 256, 0, stream>>>(Wv, (unsigned short*)Wv_bf, 4194304);
    cast_f32_bf16<<<4194304 / 256, 256, 0, stream>>>(Wo, (unsigned short*)Wo_bf, 4194304);
    transpose_wkq<<<2048, 256, 0, stream>>>(Wk, Wq, Wt);
    // K-split phase GEMM (2048 blocks -> up to 32 waves/CU) + finalize
    phase_partial<<<dim3(256, 8), 256, 0, stream>>>(x, Wt, part);
    phase_finalize<<<2048, 256, 0, stream>>>(part, bk, bq, scl);
    // V = (x @ Wv^T + bv) * scale  -> nbuf (bf16)
    gemm_bt<1><<<dim3(64, 32), 256, 0, stream>>>(x_bf, Wv_bf, bv, scl, nullptr,
                                                 nbuf, nullptr, DIM);
    // LayerNorm in place
    ln_kernel<<<8192, 256, 0, stream>>>(nbuf, lng, lnb);
    // out = x + normed @ Wo^T + bo  (fp32 out)
    gemm_bt<2><<<dim3(64, 32), 256, 0, stream>>>(nbuf, Wo_bf, bo, nullptr, x,
                                                 nullptr, (float*)d_out, DIM);
}

// Round 2
// 1120.028 us; speedup vs baseline: 1.5552x; 1.2346x over previous
//
#include <hip/hip_runtime.h>
#include <hip/hip_bf16.h>
#include <math.h>
#include <stdint.h>

#define PI_F 3.14159265358979323846f

typedef __hip_bfloat16 bf16;
typedef __attribute__((ext_vector_type(8))) short short8;   // 8 x bf16 (4 VGPRs)
typedef __attribute__((ext_vector_type(4))) float floatx4;

static constexpr int DIM = 4096;

// ---------- helpers ----------
__device__ __forceinline__ unsigned short f2bf_bits(float f) {
    __hip_bfloat16 h = __float2bfloat16(f);
    return __builtin_bit_cast(unsigned short, h);
}
__device__ __forceinline__ float bf2f_bits(unsigned short u) {
    return __builtin_bit_cast(float, ((unsigned int)u) << 16);
}
// async global->LDS, 16B per lane; LDS dest is wave-uniform base (+lane*16 implicit)
__device__ __forceinline__ void load_lds16(const void* gsrc, void* lds) {
    __builtin_amdgcn_global_load_lds(
        (__attribute__((address_space(1))) void*)gsrc,
        (__attribute__((address_space(3))) void*)lds,
        16, 0, 0);
}

// ---------- cast fp32 -> bf16, 4 elems/thread ----------
__global__ __launch_bounds__(256)
void cast_f32_bf16(const float* __restrict__ src, unsigned short* __restrict__ dst, int n4) {
    int i = blockIdx.x * 256 + threadIdx.x;
    if (i < n4) {
        float4 v = ((const float4*)src)[i];
        ushort4 o;
        o.x = f2bf_bits(v.x); o.y = f2bf_bits(v.y);
        o.z = f2bf_bits(v.z); o.w = f2bf_bits(v.w);
        ((ushort4*)dst)[i] = o;
    }
}

// ---------- pack Wk,Wq into Wt[k][p] fp32 (p<64: Wk, p>=64: Wq) ----------
__global__ __launch_bounds__(256)
void transpose_wkq(const float* __restrict__ Wk, const float* __restrict__ Wq,
                   float* __restrict__ Wt) {
    int idx = blockIdx.x * 256 + threadIdx.x;   // over 4096*128
    int k = idx >> 7, p = idx & 127;
    float v = (p < 64) ? Wk[(size_t)p * DIM + k] : Wq[(size_t)(p - 64) * DIM + k];
    Wt[idx] = v;
}

// ---------- phase GEMM, K-split partials (fp32, exact) ----------
__global__ __launch_bounds__(256)
void phase_partial(const float* __restrict__ x, const float* __restrict__ Wt,
                   float* __restrict__ part)
{
    const int tid = threadIdx.x;
    const int rg  = tid >> 5;          // 0..7 -> rows rg*4..+4
    const int cg  = tid & 31;          // 0..31 -> cols cg*4..+4
    const size_t row0 = (size_t)blockIdx.x * 32;
    const int s   = blockIdx.y;        // K slice 0..7
    const int kbeg = s * 512, kend = kbeg + 512;

    float acc[4][4] = {};
    const float* xp = x + (row0 + (size_t)rg * 4) * DIM;

    for (int k = kbeg; k < kend; k += 4) {
        const float4 w0 = *(const float4*)(Wt + (size_t)(k + 0) * 128 + cg * 4);
        const float4 w1 = *(const float4*)(Wt + (size_t)(k + 1) * 128 + cg * 4);
        const float4 w2 = *(const float4*)(Wt + (size_t)(k + 2) * 128 + cg * 4);
        const float4 w3 = *(const float4*)(Wt + (size_t)(k + 3) * 128 + cg * 4);
        #pragma unroll
        for (int r = 0; r < 4; ++r) {
            const float4 xv = *(const float4*)(xp + (size_t)r * DIM + k);
            acc[r][0] += xv.x * w0.x + xv.y * w1.x + xv.z * w2.x + xv.w * w3.x;
            acc[r][1] += xv.x * w0.y + xv.y * w1.y + xv.z * w2.y + xv.w * w3.y;
            acc[r][2] += xv.x * w0.z + xv.y * w1.z + xv.z * w2.z + xv.w * w3.z;
            acc[r][3] += xv.x * w0.w + xv.y * w1.w + xv.z * w2.w + xv.w * w3.w;
        }
    }

    #pragma unroll
    for (int r = 0; r < 4; ++r) {
        float4 st;
        st.x = acc[r][0]; st.y = acc[r][1]; st.z = acc[r][2]; st.w = acc[r][3];
        *(float4*)(part + ((size_t)s * 8192 + row0 + rg * 4 + r) * 128 + cg * 4) = st;
    }
}

// ---------- finalize: sum K slices, tanh/cos/softplus -> scale[row] ----------
__global__ __launch_bounds__(256)
void phase_finalize(const float* __restrict__ part, const float* __restrict__ bk,
                    const float* __restrict__ bq, float* __restrict__ scale)
{
    const int tid  = threadIdx.x;
    const int lane = tid & 63;
    const size_t row = (size_t)blockIdx.x * 4 + (tid >> 6);
    float sk = 0.f, sq = 0.f;
    #pragma unroll
    for (int s = 0; s < 8; ++s) {
        const float* pr = part + ((size_t)s * 8192 + row) * 128;
        sk += pr[lane];
        sq += pr[64 + lane];
    }
    const float kp = PI_F * tanhf(sk + bk[lane]);
    const float qp = PI_F * tanhf(sq + bq[lane]);
    float c = cosf(kp - qp);
    #pragma unroll
    for (int off = 32; off; off >>= 1) c += __shfl_down(c, off, 64);
    if (lane == 0) {
        const float a = c;
        const float gsp = log1pf(expf(a * (1.f / 64.f) + 0.5f));   // softplus
        scale[row] = a * gsp * (1.f / 64.f);
    }
}

// ============================================================================
// 256x256-tile 8-phase bf16 MFMA GEMM (T2 swizzle + T3/T4 counted vmcnt + T5).
// C[m][n] = sum_k A[m][k]*Bm[n][k]  (Bm is [N][K] row-major, i.e. B^T input)
// MODE 1: outBf = bf16( (dot + bias[n]) * scale[m] )
// MODE 2: outF  = fp32( dot + bias[n] + xres[m][n] )
//
// Geometry: BM=BN=256, BK=64, 512 thr = 8 waves (2M x 4N), per-wave 128x64 out.
// LDS: [buf2][A/B][256 rows][64 k] bf16 = 128 KiB, double-buffered per K-tile.
// Window w (4 phases) computes K-tile w from buf[w&1]; phase (MH,KS) does
// 16 MFMA = 4 M_rep x 4 N_rep at k-step KS.  Region staging schedule (each
// region staged strictly after its last-reader phase, barrier-separated):
//   ph0: stage B(w+1) rows 0-127    ph1: stage B(w+1) rows 128-255 ; vmcnt(6)
//   ph2: stage A(w+1) rows 64-127,192-255 (mh1)
//   ph3: stage A(w+2) rows 0-63,128-191 (mh0, same buf, freed at ph1); vmcnt(4)
// LDS swizzle: chunk' = chunk ^ (row&7) (16B granularity) on both the
// pre-swizzled global source of global_load_lds and the ds_read address.
// ============================================================================
#define VM6 asm volatile("s_waitcnt vmcnt(6)" ::: "memory")
#define VM4 asm volatile("s_waitcnt vmcnt(4)" ::: "memory")
#define VM2 asm volatile("s_waitcnt vmcnt(2)" ::: "memory")
#define VM0 asm volatile("s_waitcnt vmcnt(0)" ::: "memory")
#define VMNONE

#define STAGE_A(buf, t, R0) load_lds16(A  + gAoff + (size_t)(R0) * 4096 + (size_t)(t) * 64, \
                                       smem + (buf) * 32768 + ((R0) + (wv << 3)) * 64)
#define STAGE_B(buf, t, R0) load_lds16(Bm + gBoff + (size_t)(R0) * 4096 + (size_t)(t) * 64, \
                                       smem + (buf) * 32768 + 16384 + ((R0) + (wv << 3)) * 64)

#define MM(MH, i, j, af, bfv) \
    acc[(MH) * 4 + (i)][(j)] = __builtin_amdgcn_mfma_f32_16x16x32_bf16((af), (bfv), acc[(MH) * 4 + (i)][(j)], 0, 0, 0)

#define PHASE(BUF, MH, KS, STAGES, WAITS) do {                                   \
    const int swzc = ((((KS) * 4) + q) ^ (m16 & 7)) * 8;                         \
    const bf16* pa = smem + (BUF) * 32768 + arow0 + (MH) * 4096 + swzc;          \
    const bf16* pb = smem + (BUF) * 32768 + 16384 + brow0 + swzc;                \
    short8 a0 = *(const short8*)(pa);                                            \
    short8 a1 = *(const short8*)(pa + 1024);                                     \
    short8 a2 = *(const short8*)(pa + 2048);                                     \
    short8 a3 = *(const short8*)(pa + 3072);                                     \
    short8 b0 = *(const short8*)(pb);                                            \
    short8 b1 = *(const short8*)(pb + 1024);                                     \
    short8 b2 = *(const short8*)(pb + 2048);                                     \
    short8 b3 = *(const short8*)(pb + 3072);                                     \
    STAGES;                                                                      \
    __builtin_amdgcn_s_barrier();                                                \
    __builtin_amdgcn_s_setprio(1);                                               \
    MM(MH,0,0,a0,b0); MM(MH,0,1,a0,b1); MM(MH,0,2,a0,b2); MM(MH,0,3,a0,b3);      \
    MM(MH,1,0,a1,b0); MM(MH,1,1,a1,b1); MM(MH,1,2,a1,b2); MM(MH,1,3,a1,b3);      \
    MM(MH,2,0,a2,b0); MM(MH,2,1,a2,b1); MM(MH,2,2,a2,b2); MM(MH,2,3,a2,b3);      \
    MM(MH,3,0,a3,b0); MM(MH,3,1,a3,b1); MM(MH,3,2,a3,b2); MM(MH,3,3,a3,b3);      \
    __builtin_amdgcn_s_setprio(0);                                               \
    WAITS;                                                                       \
    __builtin_amdgcn_s_barrier();                                                \
} while (0)

#define WINDOW(W, BUF, DOB, DOA1, DOA0, W1, W3)                                  \
    do {                                                                         \
        PHASE(BUF, 0, 0,                                                         \
              if (DOB) { STAGE_B((BUF) ^ 1, (W) + 1, 0); STAGE_B((BUF) ^ 1, (W) + 1, 64); },  \
              VMNONE);                                                           \
        PHASE(BUF, 0, 1,                                                         \
              if (DOB) { STAGE_B((BUF) ^ 1, (W) + 1, 128); STAGE_B((BUF) ^ 1, (W) + 1, 192); }, \
              W1);                                                               \
        PHASE(BUF, 1, 0,                                                         \
              if (DOA1) { STAGE_A((BUF) ^ 1, (W) + 1, 64); STAGE_A((BUF) ^ 1, (W) + 1, 192); }, \
              VMNONE);                                                           \
        PHASE(BUF, 1, 1,                                                         \
              if (DOA0) { STAGE_A((BUF), (W) + 2, 0); STAGE_A((BUF), (W) + 2, 128); },          \
              W3);                                                               \
    } while (0)

template <int MODE>
__global__ __launch_bounds__(512, 2)
void gemm256(const bf16* __restrict__ A, const bf16* __restrict__ Bm,
             const float* __restrict__ bias, const float* __restrict__ scale,
             const float* __restrict__ xres, bf16* __restrict__ outBf,
             float* __restrict__ outF)
{
    __shared__ __align__(16) bf16 smem[2 * 2 * 256 * 64];   // 128 KiB

    const int tid  = threadIdx.x;
    const int lane = tid & 63;
    const int wv   = tid >> 6;        // 0..7
    const int wm   = wv >> 2;         // 0..1
    const int wn   = wv & 3;          // 0..3
    const int q    = lane >> 4;       // 0..3
    const int m16  = lane & 15;

    // bijective XCD swizzle over 512 blocks (512 % 8 == 0)
    const int lid = blockIdx.x;
    const int swz = (lid & 7) * 64 + (lid >> 3);
    const size_t bm = (size_t)(swz & 31) * 256;   // 32 row tiles
    const size_t bn = (size_t)(swz >> 5) * 256;   // 16 col tiles

    // staging lane geometry: wave wv covers rows R0+wv*8..+8 of a 64-row region;
    // lane: row = wv*8 + (lane>>3), fetched k-chunk = (lane&7) ^ (lane>>3)
    // (pre-swizzled source so LDS[r][c] = global[r][c ^ (r&7)])
    const int srow = (wv << 3) + (lane >> 3);
    const int schk = (lane & 7) ^ (lane >> 3);
    const size_t gAoff = (bm + srow) * 4096 + schk * 8;   // element offsets
    const size_t gBoff = (bn + srow) * 4096 + schk * 8;

    // ds_read fragment bases (element offsets); per-phase add MH*4096 + swzc
    const int arow0 = (wm * 128 + m16) * 64;
    const int brow0 = (wn * 64 + m16) * 64;

    floatx4 acc[8][4] = {};

    // ---- prologue: tile0 all 8 regions + tile1's A-mh0 ----
    STAGE_A(0, 0, 0);  STAGE_A(0, 0, 64);  STAGE_A(0, 0, 128); STAGE_A(0, 0, 192);
    STAGE_B(0, 0, 0);  STAGE_B(0, 0, 64);  STAGE_B(0, 0, 128); STAGE_B(0, 0, 192);
    STAGE_A(1, 1, 0);  STAGE_A(1, 1, 128);
    VM2;
    __builtin_amdgcn_s_barrier();

    // ---- main: windows 0..61 fully staged, then 62/63 drain ----
    for (int w = 0; w < 62; w += 2) {
        WINDOW(w,     0, 1, 1, 1, VM6, VM4);
        WINDOW(w + 1, 1, 1, 1, 1, VM6, VM4);
    }
    WINDOW(62, 0, 1, 1, 0, VM6, VM2);
    WINDOW(63, 1, 0, 0, 0, VM0, VMNONE);

    // ---- epilogue: C/D layout col=lane&15, row=(lane>>4)*4+reg ----
    #pragma unroll
    for (int ii = 0; ii < 8; ++ii) {
        const int mh = ii >> 2, i = ii & 3;
        #pragma unroll
        for (int j = 0; j < 4; ++j) {
            const size_t col = bn + wn * 64 + j * 16 + m16;
            const float bvv = bias[col];
            #pragma unroll
            for (int r = 0; r < 4; ++r) {
                const size_t row = bm + wm * 128 + mh * 64 + i * 16 + q * 4 + r;
                float v = acc[ii][j][r] + bvv;
                if (MODE == 1) {
                    v *= scale[row];
                    outBf[row * 4096 + col] = __float2bfloat16(v);
                } else {
                    v += xres[row * 4096 + col];
                    outF[row * 4096 + col] = v;
                }
            }
        }
    }
}

// ---------- in-place LayerNorm over each row of bf16 buffer ----------
__global__ __launch_bounds__(256)
void ln_kernel(bf16* __restrict__ o, const float* __restrict__ g, const float* __restrict__ b)
{
    const size_t row = blockIdx.x;
    unsigned short* p = (unsigned short*)(o + row * DIM);
    const int tid = threadIdx.x;
    float s = 0.f, s2 = 0.f;
    float vals[16];
    #pragma unroll
    for (int c = 0; c < 4; ++c) {
        ushort4 u = ((const ushort4*)p)[tid + c * 256];
        float v0 = bf2f_bits(u.x), v1 = bf2f_bits(u.y);
        float v2 = bf2f_bits(u.z), v3 = bf2f_bits(u.w);
        vals[c * 4 + 0] = v0; vals[c * 4 + 1] = v1;
        vals[c * 4 + 2] = v2; vals[c * 4 + 3] = v3;
        s  += v0 + v1 + v2 + v3;
        s2 += v0 * v0 + v1 * v1 + v2 * v2 + v3 * v3;
    }
    #pragma unroll
    for (int off = 32; off; off >>= 1) {
        s  += __shfl_down(s, off, 64);
        s2 += __shfl_down(s2, off, 64);
    }
    __shared__ float red[2][4];
    const int wv = tid >> 6, ln = tid & 63;
    if (ln == 0) { red[0][wv] = s; red[1][wv] = s2; }
    __syncthreads();
    const float ts  = red[0][0] + red[0][1] + red[0][2] + red[0][3];
    const float ts2 = red[1][0] + red[1][1] + red[1][2] + red[1][3];
    const float mean = ts * (1.f / 4096.f);
    const float var  = ts2 * (1.f / 4096.f) - mean * mean;
    const float rstd = rsqrtf(var + 1e-5f);
    #pragma unroll
    for (int c = 0; c < 4; ++c) {
        const int idx = (tid + c * 256) * 4;
        ushort4 u;
        u.x = f2bf_bits((vals[c * 4 + 0] - mean) * rstd * g[idx + 0] + b[idx + 0]);
        u.y = f2bf_bits((vals[c * 4 + 1] - mean) * rstd * g[idx + 1] + b[idx + 1]);
        u.z = f2bf_bits((vals[c * 4 + 2] - mean) * rstd * g[idx + 2] + b[idx + 2]);
        u.w = f2bf_bits((vals[c * 4 + 3] - mean) * rstd * g[idx + 3] + b[idx + 3]);
        ((ushort4*)p)[tid + c * 256] = u;
    }
}

extern "C" void kernel_launch(void* const* d_in, const int* in_sizes, int n_in,
                              void* d_out, int out_size, void* d_ws, size_t ws_size,
                              hipStream_t stream)
{
    const float* x   = (const float*)d_in[0];
    const float* Wk  = (const float*)d_in[1];
    const float* bk  = (const float*)d_in[2];
    const float* Wq  = (const float*)d_in[3];
    const float* bq  = (const float*)d_in[4];
    const float* Wv  = (const float*)d_in[5];
    const float* bv  = (const float*)d_in[6];
    const float* lng = (const float*)d_in[7];
    const float* lnb = (const float*)d_in[8];
    const float* Wo  = (const float*)d_in[9];
    const float* bo  = (const float*)d_in[10];

    char* ws = (char*)d_ws;
    bf16*  x_bf  = (bf16*)(ws);                       //  64 MiB  [8192][4096]
    bf16*  Wv_bf = (bf16*)(ws + 67108864);            //  32 MiB  [4096][4096]
    bf16*  Wo_bf = (bf16*)(ws + 100663296);           //  32 MiB  [4096][4096]
    float* Wt    = (float*)(ws + 134217728);          //   2 MiB  [4096][128]
    float* scl   = (float*)(ws + 136314880);          //  32 KiB  [8192]
    bf16*  nbuf  = (bf16*)(ws + 136347648);           //  64 MiB  [8192][4096]
    // phase partials alias the nbuf region (33.5 MiB < 64 MiB): fully consumed
    // by phase_finalize before gemm256<1> writes nbuf.
    float* part  = (float*)nbuf;                      //  [8][8192][128] fp32

    cast_f32_bf16<<<8388608 / 256, 256, 0, stream>>>(x,  (unsigned short*)x_bf,  8388608);
    cast_f32_bf16<<<4194304 / 256, 256, 0, stream>>>(Wv, (unsigned short*)Wv_bf, 4194304);
    cast_f32_bf16<<<4194304 / 256, 256, 0, stream>>>(Wo, (unsigned short*)Wo_bf, 4194304);
    transpose_wkq<<<2048, 256, 0, stream>>>(Wk, Wq, Wt);
    // K-split phase GEMM (2048 blocks -> up to 32 waves/CU) + finalize
    phase_partial<<<dim3(256, 8), 256, 0, stream>>>(x, Wt, part);
    phase_finalize<<<2048, 256, 0, stream>>>(part, bk, bq, scl);
    // V = (x @ Wv^T + bv) * scale  -> nbuf (bf16)
    gemm256<1><<<512, 512, 0, stream>>>(x_bf, Wv_bf, bv, scl, nullptr, nbuf, nullptr);
    // LayerNorm in place
    ln_kernel<<<8192, 256, 0, stream>>>(nbuf, lng, lnb);
    // out = x + normed @ Wo^T + bo  (fp32 out)
    gemm256<2><<<512, 512, 0, stream>>>(nbuf, Wo_bf, bo, nullptr, x, nullptr, (float*)d_out);
}

// Round 3
// 945.199 us; speedup vs baseline: 1.8428x; 1.1850x over previous
//
#include <hip/hip_runtime.h>
#include <hip/hip_bf16.h>
#include <math.h>
#include <stdint.h>

#define PI_F 3.14159265358979323846f

typedef __hip_bfloat16 bf16;
typedef __attribute__((ext_vector_type(8))) short short8;   // 8 x bf16 (4 VGPRs)
typedef __attribute__((ext_vector_type(4))) float floatx4;

static constexpr int DIM = 4096;

// ---------- helpers ----------
__device__ __forceinline__ unsigned short f2bf_bits(float f) {
    __hip_bfloat16 h = __float2bfloat16(f);
    return __builtin_bit_cast(unsigned short, h);
}
__device__ __forceinline__ float bf2f_bits(unsigned short u) {
    return __builtin_bit_cast(float, ((unsigned int)u) << 16);
}
// async global->LDS, 16B per lane; LDS dest is wave-uniform base (+lane*16 implicit)
__device__ __forceinline__ void load_lds16(const void* gsrc, void* lds) {
    __builtin_amdgcn_global_load_lds(
        (__attribute__((address_space(1))) void*)gsrc,
        (__attribute__((address_space(3))) void*)lds,
        16, 0, 0);
}

// ---------- cast fp32 -> bf16, 4 elems/thread ----------
__global__ __launch_bounds__(256)
void cast_f32_bf16(const float* __restrict__ src, unsigned short* __restrict__ dst, int n4) {
    int i = blockIdx.x * 256 + threadIdx.x;
    if (i < n4) {
        float4 v = ((const float4*)src)[i];
        ushort4 o;
        o.x = f2bf_bits(v.x); o.y = f2bf_bits(v.y);
        o.z = f2bf_bits(v.z); o.w = f2bf_bits(v.w);
        ((ushort4*)dst)[i] = o;
    }
}

// ---------- cast fp32 -> bf16 hi + lo residual (split-bf16 for exact-ish MFMA) ----------
__global__ __launch_bounds__(256)
void cast_f32_bf16_hilo(const float* __restrict__ src, unsigned short* __restrict__ hi,
                        unsigned short* __restrict__ lo, int n4) {
    int i = blockIdx.x * 256 + threadIdx.x;
    if (i < n4) {
        float4 v = ((const float4*)src)[i];
        ushort4 h, l;
        h.x = f2bf_bits(v.x); l.x = f2bf_bits(v.x - bf2f_bits(h.x));
        h.y = f2bf_bits(v.y); l.y = f2bf_bits(v.y - bf2f_bits(h.y));
        h.z = f2bf_bits(v.z); l.z = f2bf_bits(v.z - bf2f_bits(h.z));
        h.w = f2bf_bits(v.w); l.w = f2bf_bits(v.w - bf2f_bits(h.w));
        ((ushort4*)hi)[i] = h;
        ((ushort4*)lo)[i] = l;
    }
}

// ---------- cast Wk|Wq (concat rows, already [N][K]) -> bf16 hi/lo ----------
__global__ __launch_bounds__(256)
void cast_wkq_hilo(const float* __restrict__ Wk, const float* __restrict__ Wq,
                   unsigned short* __restrict__ hi, unsigned short* __restrict__ lo) {
    int i = blockIdx.x * 256 + threadIdx.x;       // over 128*4096/4 float4s
    const int n = i >> 10;                        // row 0..127 (1024 float4/row)
    const int c4 = i & 1023;
    const float* src = (n < 64) ? (Wk + (size_t)n * DIM) : (Wq + (size_t)(n - 64) * DIM);
    float4 v = ((const float4*)src)[c4];
    ushort4 h, l;
    h.x = f2bf_bits(v.x); l.x = f2bf_bits(v.x - bf2f_bits(h.x));
    h.y = f2bf_bits(v.y); l.y = f2bf_bits(v.y - bf2f_bits(h.y));
    h.z = f2bf_bits(v.z); l.z = f2bf_bits(v.z - bf2f_bits(h.z));
    h.w = f2bf_bits(v.w); l.w = f2bf_bits(v.w - bf2f_bits(h.w));
    ((ushort4*)hi)[i] = h;
    ((ushort4*)lo)[i] = l;
}

// ============================================================================
// phase GEMM via split-bf16 MFMA: part[s][m][n] = sum_{k in slice s} x[m][k]*W[n][k]
// dot = xh*wh + xh*wl + xl*wh  (xl*wl dropped, ~2^-18 relative).
// BM=64, BN=128 (full P width), K-slice 512, grid (128, 8) = 1024 blocks (4/CU).
// 256 thr = 4 waves (2M x 2N), wave tile 32x64, acc[2][4].
// LDS 24 KB: Ah[64][32] Al[64][32] Bh[128][32] Bl[128][32], global_load_lds
// staged with pre-swizzled source chunk c^(r&3)^((r>>2)&3); ds_read applies the
// same swizzle -> max 2-way bank aliasing (free).
// ============================================================================
__global__ __launch_bounds__(256)
void phase_mfma(const bf16* __restrict__ xh, const bf16* __restrict__ xl,
                const bf16* __restrict__ wh, const bf16* __restrict__ wl,
                float* __restrict__ part)
{
    __shared__ __align__(16) bf16 sm[12288];   // 24 KiB
    const int tid  = threadIdx.x;
    const int lane = tid & 63;
    const int wv   = tid >> 6;        // 0..3
    const int wm   = wv >> 1;         // 0..1
    const int wn   = wv & 1;          // 0..1
    const int q    = lane >> 4;       // 0..3
    const int m16  = lane & 15;

    const size_t bm = (size_t)blockIdx.x * 64;
    const int s    = blockIdx.y;
    const int kbeg = s * 512;

    // staging lane geometry: lane -> (row-in-16 = lane>>2, lds chunk = lane&3);
    // source chunk pre-swizzled so LDS[r][c] = global[r][c ^ (r&3) ^ ((r>>2)&3)]
    const int sr = lane >> 2;
    const int sc = (lane & 3) ^ (sr & 3) ^ ((sr >> 2) & 3);
    const size_t gA  = (bm + (size_t)wv * 16 + sr) * 4096 + kbeg + sc * 8;
    const size_t gB0 = ((size_t)wv * 32 + sr) * 4096 + kbeg + sc * 8;
    const size_t gB1 = gB0 + (size_t)16 * 4096;

    bf16* lAh  = sm + wv * 512;                 // A rows wv*16..+16
    bf16* lAl  = sm + 2048 + wv * 512;
    bf16* lBh0 = sm + 4096 + wv * 1024;         // B rows wv*32..+16
    bf16* lBh1 = sm + 4096 + wv * 1024 + 512;   // B rows wv*32+16..+16
    bf16* lBl0 = sm + 8192 + wv * 1024;
    bf16* lBl1 = sm + 8192 + wv * 1024 + 512;

    // frag read addressing (loop-invariant): row swz = (m16&3)^((m16>>2)&3)
    const int sl    = ((q ^ ((m16 & 3) ^ ((m16 >> 2) & 3))) * 8);
    const int aoff0 = (wm * 32 + m16) * 32 + sl;
    const int aoff1 = aoff0 + 16 * 32;

    floatx4 acc[2][4] = {};

    for (int t = 0; t < 16; ++t) {
        const size_t ko = (size_t)t * 32;
        load_lds16(xh + gA  + ko, lAh);
        load_lds16(xl + gA  + ko, lAl);
        load_lds16(wh + gB0 + ko, lBh0);
        load_lds16(wh + gB1 + ko, lBh1);
        load_lds16(wl + gB0 + ko, lBl0);
        load_lds16(wl + gB1 + ko, lBl1);
        __syncthreads();
        short8 ah0 = *(const short8*)(sm + aoff0);
        short8 ah1 = *(const short8*)(sm + aoff1);
        short8 al0 = *(const short8*)(sm + 2048 + aoff0);
        short8 al1 = *(const short8*)(sm + 2048 + aoff1);
        short8 bh[4], bl[4];
        #pragma unroll
        for (int j = 0; j < 4; ++j) {
            const int boff = (wn * 64 + j * 16 + m16) * 32 + sl;
            bh[j] = *(const short8*)(sm + 4096 + boff);
            bl[j] = *(const short8*)(sm + 8192 + boff);
        }
        #pragma unroll
        for (int j = 0; j < 4; ++j) {
            acc[0][j] = __builtin_amdgcn_mfma_f32_16x16x32_bf16(ah0, bh[j], acc[0][j], 0, 0, 0);
            acc[0][j] = __builtin_amdgcn_mfma_f32_16x16x32_bf16(ah0, bl[j], acc[0][j], 0, 0, 0);
            acc[0][j] = __builtin_amdgcn_mfma_f32_16x16x32_bf16(al0, bh[j], acc[0][j], 0, 0, 0);
            acc[1][j] = __builtin_amdgcn_mfma_f32_16x16x32_bf16(ah1, bh[j], acc[1][j], 0, 0, 0);
            acc[1][j] = __builtin_amdgcn_mfma_f32_16x16x32_bf16(ah1, bl[j], acc[1][j], 0, 0, 0);
            acc[1][j] = __builtin_amdgcn_mfma_f32_16x16x32_bf16(al1, bh[j], acc[1][j], 0, 0, 0);
        }
        __syncthreads();
    }

    // epilogue: C/D layout col=lane&15, row=(lane>>4)*4+reg
    #pragma unroll
    for (int i = 0; i < 2; ++i) {
        #pragma unroll
        for (int j = 0; j < 4; ++j) {
            const int col = wn * 64 + j * 16 + m16;
            #pragma unroll
            for (int r = 0; r < 4; ++r) {
                const size_t row = bm + wm * 32 + i * 16 + q * 4 + r;
                part[((size_t)s * 8192 + row) * 128 + col] = acc[i][j][r];
            }
        }
    }
}

// ---------- finalize: sum K slices, tanh/cos/softplus -> scale[row] ----------
__global__ __launch_bounds__(256)
void phase_finalize(const float* __restrict__ part, const float* __restrict__ bk,
                    const float* __restrict__ bq, float* __restrict__ scale)
{
    const int tid  = threadIdx.x;
    const int lane = tid & 63;
    const size_t row = (size_t)blockIdx.x * 4 + (tid >> 6);
    float sk = 0.f, sq = 0.f;
    #pragma unroll
    for (int s = 0; s < 8; ++s) {
        const float* pr = part + ((size_t)s * 8192 + row) * 128;
        sk += pr[lane];
        sq += pr[64 + lane];
    }
    const float kp = PI_F * tanhf(sk + bk[lane]);
    const float qp = PI_F * tanhf(sq + bq[lane]);
    float c = cosf(kp - qp);
    #pragma unroll
    for (int off = 32; off; off >>= 1) c += __shfl_down(c, off, 64);
    if (lane == 0) {
        const float a = c;
        const float gsp = log1pf(expf(a * (1.f / 64.f) + 0.5f));   // softplus
        scale[row] = a * gsp * (1.f / 64.f);
    }
}

// ============================================================================
// 256x256-tile 8-phase bf16 MFMA GEMM (T2 swizzle + T3/T4 counted vmcnt + T5).
// (unchanged from round 1 — see comments there)
// ============================================================================
#define VM6 asm volatile("s_waitcnt vmcnt(6)" ::: "memory")
#define VM4 asm volatile("s_waitcnt vmcnt(4)" ::: "memory")
#define VM2 asm volatile("s_waitcnt vmcnt(2)" ::: "memory")
#define VM0 asm volatile("s_waitcnt vmcnt(0)" ::: "memory")
#define VMNONE

#define STAGE_A(buf, t, R0) load_lds16(A  + gAoff + (size_t)(R0) * 4096 + (size_t)(t) * 64, \
                                       smem + (buf) * 32768 + ((R0) + (wv << 3)) * 64)
#define STAGE_B(buf, t, R0) load_lds16(Bm + gBoff + (size_t)(R0) * 4096 + (size_t)(t) * 64, \
                                       smem + (buf) * 32768 + 16384 + ((R0) + (wv << 3)) * 64)

#define MM(MH, i, j, af, bfv) \
    acc[(MH) * 4 + (i)][(j)] = __builtin_amdgcn_mfma_f32_16x16x32_bf16((af), (bfv), acc[(MH) * 4 + (i)][(j)], 0, 0, 0)

#define PHASE(BUF, MH, KS, STAGES, WAITS) do {                                   \
    const int swzc = ((((KS) * 4) + q) ^ (m16 & 7)) * 8;                         \
    const bf16* pa = smem + (BUF) * 32768 + arow0 + (MH) * 4096 + swzc;          \
    const bf16* pb = smem + (BUF) * 32768 + 16384 + brow0 + swzc;                \
    short8 a0 = *(const short8*)(pa);                                            \
    short8 a1 = *(const short8*)(pa + 1024);                                     \
    short8 a2 = *(const short8*)(pa + 2048);                                     \
    short8 a3 = *(const short8*)(pa + 3072);                                     \
    short8 b0 = *(const short8*)(pb);                                            \
    short8 b1 = *(const short8*)(pb + 1024);                                     \
    short8 b2 = *(const short8*)(pb + 2048);                                     \
    short8 b3 = *(const short8*)(pb + 3072);                                     \
    STAGES;                                                                      \
    __builtin_amdgcn_s_barrier();                                                \
    __builtin_amdgcn_s_setprio(1);                                               \
    MM(MH,0,0,a0,b0); MM(MH,0,1,a0,b1); MM(MH,0,2,a0,b2); MM(MH,0,3,a0,b3);      \
    MM(MH,1,0,a1,b0); MM(MH,1,1,a1,b1); MM(MH,1,2,a1,b2); MM(MH,1,3,a1,b3);      \
    MM(MH,2,0,a2,b0); MM(MH,2,1,a2,b1); MM(MH,2,2,a2,b2); MM(MH,2,3,a2,b3);      \
    MM(MH,3,0,a3,b0); MM(MH,3,1,a3,b1); MM(MH,3,2,a3,b2); MM(MH,3,3,a3,b3);      \
    __builtin_amdgcn_s_setprio(0);                                               \
    WAITS;                                                                       \
    __builtin_amdgcn_s_barrier();                                                \
} while (0)

#define WINDOW(W, BUF, DOB, DOA1, DOA0, W1, W3)                                  \
    do {                                                                         \
        PHASE(BUF, 0, 0,                                                         \
              if (DOB) { STAGE_B((BUF) ^ 1, (W) + 1, 0); STAGE_B((BUF) ^ 1, (W) + 1, 64); },  \
              VMNONE);                                                           \
        PHASE(BUF, 0, 1,                                                         \
              if (DOB) { STAGE_B((BUF) ^ 1, (W) + 1, 128); STAGE_B((BUF) ^ 1, (W) + 1, 192); }, \
              W1);                                                               \
        PHASE(BUF, 1, 0,                                                         \
              if (DOA1) { STAGE_A((BUF) ^ 1, (W) + 1, 64); STAGE_A((BUF) ^ 1, (W) + 1, 192); }, \
              VMNONE);                                                           \
        PHASE(BUF, 1, 1,                                                         \
              if (DOA0) { STAGE_A((BUF), (W) + 2, 0); STAGE_A((BUF), (W) + 2, 128); },          \
              W3);                                                               \
    } while (0)

template <int MODE>
__global__ __launch_bounds__(512, 2)
void gemm256(const bf16* __restrict__ A, const bf16* __restrict__ Bm,
             const float* __restrict__ bias, const float* __restrict__ scale,
             const float* __restrict__ xres, bf16* __restrict__ outBf,
             float* __restrict__ outF)
{
    __shared__ __align__(16) bf16 smem[2 * 2 * 256 * 64];   // 128 KiB

    const int tid  = threadIdx.x;
    const int lane = tid & 63;
    const int wv   = tid >> 6;        // 0..7
    const int wm   = wv >> 2;         // 0..1
    const int wn   = wv & 3;          // 0..3
    const int q    = lane >> 4;       // 0..3
    const int m16  = lane & 15;

    // bijective XCD swizzle over 512 blocks (512 % 8 == 0)
    const int lid = blockIdx.x;
    const int swz = (lid & 7) * 64 + (lid >> 3);
    const size_t bm = (size_t)(swz & 31) * 256;   // 32 row tiles
    const size_t bn = (size_t)(swz >> 5) * 256;   // 16 col tiles

    // staging lane geometry: wave wv covers rows R0+wv*8..+8 of a 64-row region;
    // lane: row = wv*8 + (lane>>3), fetched k-chunk = (lane&7) ^ (lane>>3)
    // (pre-swizzled source so LDS[r][c] = global[r][c ^ (r&7)])
    const int srow = (wv << 3) + (lane >> 3);
    const int schk = (lane & 7) ^ (lane >> 3);
    const size_t gAoff = (bm + srow) * 4096 + schk * 8;   // element offsets
    const size_t gBoff = (bn + srow) * 4096 + schk * 8;

    // ds_read fragment bases (element offsets); per-phase add MH*4096 + swzc
    const int arow0 = (wm * 128 + m16) * 64;
    const int brow0 = (wn * 64 + m16) * 64;

    floatx4 acc[8][4] = {};

    // ---- prologue: tile0 all 8 regions + tile1's A-mh0 ----
    STAGE_A(0, 0, 0);  STAGE_A(0, 0, 64);  STAGE_A(0, 0, 128); STAGE_A(0, 0, 192);
    STAGE_B(0, 0, 0);  STAGE_B(0, 0, 64);  STAGE_B(0, 0, 128); STAGE_B(0, 0, 192);
    STAGE_A(1, 1, 0);  STAGE_A(1, 1, 128);
    VM2;
    __builtin_amdgcn_s_barrier();

    // ---- main: windows 0..61 fully staged, then 62/63 drain ----
    for (int w = 0; w < 62; w += 2) {
        WINDOW(w,     0, 1, 1, 1, VM6, VM4);
        WINDOW(w + 1, 1, 1, 1, 1, VM6, VM4);
    }
    WINDOW(62, 0, 1, 1, 0, VM6, VM2);
    WINDOW(63, 1, 0, 0, 0, VM0, VMNONE);

    // ---- epilogue: C/D layout col=lane&15, row=(lane>>4)*4+reg ----
    #pragma unroll
    for (int ii = 0; ii < 8; ++ii) {
        const int mh = ii >> 2, i = ii & 3;
        #pragma unroll
        for (int j = 0; j < 4; ++j) {
            const size_t col = bn + wn * 64 + j * 16 + m16;
            const float bvv = bias[col];
            #pragma unroll
            for (int r = 0; r < 4; ++r) {
                const size_t row = bm + wm * 128 + mh * 64 + i * 16 + q * 4 + r;
                float v = acc[ii][j][r] + bvv;
                if (MODE == 1) {
                    v *= scale[row];
                    outBf[row * 4096 + col] = __float2bfloat16(v);
                } else {
                    v += xres[row * 4096 + col];
                    outF[row * 4096 + col] = v;
                }
            }
        }
    }
}

// ---------- in-place LayerNorm over each row of bf16 buffer ----------
__global__ __launch_bounds__(256)
void ln_kernel(bf16* __restrict__ o, const float* __restrict__ g, const float* __restrict__ b)
{
    const size_t row = blockIdx.x;
    unsigned short* p = (unsigned short*)(o + row * DIM);
    const int tid = threadIdx.x;
    float s = 0.f, s2 = 0.f;
    float vals[16];
    #pragma unroll
    for (int c = 0; c < 4; ++c) {
        ushort4 u = ((const ushort4*)p)[tid + c * 256];
        float v0 = bf2f_bits(u.x), v1 = bf2f_bits(u.y);
        float v2 = bf2f_bits(u.z), v3 = bf2f_bits(u.w);
        vals[c * 4 + 0] = v0; vals[c * 4 + 1] = v1;
        vals[c * 4 + 2] = v2; vals[c * 4 + 3] = v3;
        s  += v0 + v1 + v2 + v3;
        s2 += v0 * v0 + v1 * v1 + v2 * v2 + v3 * v3;
    }
    #pragma unroll
    for (int off = 32; off; off >>= 1) {
        s  += __shfl_down(s, off, 64);
        s2 += __shfl_down(s2, off, 64);
    }
    __shared__ float red[2][4];
    const int wv = tid >> 6, ln = tid & 63;
    if (ln == 0) { red[0][wv] = s; red[1][wv] = s2; }
    __syncthreads();
    const float ts  = red[0][0] + red[0][1] + red[0][2] + red[0][3];
    const float ts2 = red[1][0] + red[1][1] + red[1][2] + red[1][3];
    const float mean = ts * (1.f / 4096.f);
    const float var  = ts2 * (1.f / 4096.f) - mean * mean;
    const float rstd = rsqrtf(var + 1e-5f);
    #pragma unroll
    for (int c = 0; c < 4; ++c) {
        const int idx = (tid + c * 256) * 4;
        ushort4 u;
        u.x = f2bf_bits((vals[c * 4 + 0] - mean) * rstd * g[idx + 0] + b[idx + 0]);
        u.y = f2bf_bits((vals[c * 4 + 1] - mean) * rstd * g[idx + 1] + b[idx + 1]);
        u.z = f2bf_bits((vals[c * 4 + 2] - mean) * rstd * g[idx + 2] + b[idx + 2]);
        u.w = f2bf_bits((vals[c * 4 + 3] - mean) * rstd * g[idx + 3] + b[idx + 3]);
        ((ushort4*)p)[tid + c * 256] = u;
    }
}

extern "C" void kernel_launch(void* const* d_in, const int* in_sizes, int n_in,
                              void* d_out, int out_size, void* d_ws, size_t ws_size,
                              hipStream_t stream)
{
    const float* x   = (const float*)d_in[0];
    const float* Wk  = (const float*)d_in[1];
    const float* bk  = (const float*)d_in[2];
    const float* Wq  = (const float*)d_in[3];
    const float* bq  = (const float*)d_in[4];
    const float* Wv  = (const float*)d_in[5];
    const float* bv  = (const float*)d_in[6];
    const float* lng = (const float*)d_in[7];
    const float* lnb = (const float*)d_in[8];
    const float* Wo  = (const float*)d_in[9];
    const float* bo  = (const float*)d_in[10];

    char* ws = (char*)d_ws;
    bf16*  x_bf   = (bf16*)(ws);                      //  64 MiB  [8192][4096] (hi)
    bf16*  x_lo   = (bf16*)(ws + 67108864);           //  64 MiB  (dead after phase_mfma)
    bf16*  Wv_bf  = (bf16*)(ws + 67108864);           //  32 MiB  (aliases x_lo; cast AFTER phase)
    bf16*  Wo_bf  = (bf16*)(ws + 100663296);          //  32 MiB  (aliases x_lo hi half)
    bf16*  Wkq_hi = (bf16*)(ws + 134217728);          //   1 MiB  [128][4096]
    bf16*  Wkq_lo = (bf16*)(ws + 135266304);          //   1 MiB
    float* scl    = (float*)(ws + 136314880);         //  32 KiB  [8192]
    bf16*  nbuf   = (bf16*)(ws + 136347648);          //  64 MiB  [8192][4096]
    // phase partials alias the nbuf region (33.5 MiB < 64 MiB): fully consumed
    // by phase_finalize before gemm256<1> writes nbuf.
    float* part   = (float*)nbuf;                     //  [8][8192][128] fp32
    // total ws use: ~194 MiB (x_lo / Wv_bf+Wo_bf share by stream-ordered lifetime)

    // phase path first (x_lo occupies the Wv/Wo slots until consumed)
    cast_f32_bf16_hilo<<<8388608 / 256, 256, 0, stream>>>(x, (unsigned short*)x_bf,
                                                          (unsigned short*)x_lo, 8388608);
    cast_wkq_hilo<<<131072 / 256, 256, 0, stream>>>(Wk, Wq, (unsigned short*)Wkq_hi,
                                                    (unsigned short*)Wkq_lo);
    phase_mfma<<<dim3(128, 8), 256, 0, stream>>>(x_bf, x_lo, Wkq_hi, Wkq_lo, part);
    phase_finalize<<<2048, 256, 0, stream>>>(part, bk, bq, scl);
    // now x_lo is dead -> cast Wv/Wo into its region
    cast_f32_bf16<<<4194304 / 256, 256, 0, stream>>>(Wv, (unsigned short*)Wv_bf, 4194304);
    cast_f32_bf16<<<4194304 / 256, 256, 0, stream>>>(Wo, (unsigned short*)Wo_bf, 4194304);
    // V = (x @ Wv^T + bv) * scale  -> nbuf (bf16)
    gemm256<1><<<512, 512, 0, stream>>>(x_bf, Wv_bf, bv, scl, nullptr, nbuf, nullptr);
    // LayerNorm in place
    ln_kernel<<<8192, 256, 0, stream>>>(nbuf, lng, lnb);
    // out = x + normed @ Wo^T + bo  (fp32 out)
    gemm256<2><<<512, 512, 0, stream>>>(nbuf, Wo_bf, bo, nullptr, x, nullptr, (float*)d_out);
}